// Round 1
// baseline (568.505 us; speedup 1.0000x reference)
//
#include <hip/hip_runtime.h>
#include <math.h>

namespace {

constexpr int KK = 5;
constexpr int N0 = 16384, E0 = 262144;
constexpr int N1 = 4096,  E1 = 65536;
constexpr int N2 = 1024,  E2 = 16384;
constexpr int N3 = 256,   E3 = 4096;
constexpr int NV = 128;            // B*8 final "nodes"
constexpr int BB = 16;

// ---------------- workspace layout (float offsets) ----------------
constexpr size_t OFF_AGG1 = 0;
constexpr size_t OFF_AGG2 = OFF_AGG1 + (size_t)N0 * 32;
constexpr size_t OFF_AGG3 = OFF_AGG2 + (size_t)N1 * 64;
constexpr size_t OFF_AGG4 = OFF_AGG3 + (size_t)N2 * 64;
constexpr size_t OFF_DEG1 = OFF_AGG4 + (size_t)N3 * 128;
constexpr size_t OFF_DEG2 = OFF_DEG1 + N0;
constexpr size_t OFF_DEG3 = OFF_DEG2 + N1;
constexpr size_t OFF_DEG4 = OFF_DEG3 + N2;
constexpr size_t ZERO_END = OFF_DEG4 + N3;          // region zeroed each call

constexpr size_t OFF_PENC1 = ZERO_END;              // encoded-max pool buffers
constexpr size_t OFF_PENC2 = OFF_PENC1 + (size_t)N1 * 32;
constexpr size_t OFF_PENC3 = OFF_PENC2 + (size_t)N2 * 64;
constexpr size_t OFF_PENC4 = OFF_PENC3 + (size_t)N3 * 64;
constexpr size_t PENC_END  = OFF_PENC4 + (size_t)NV * 128;
constexpr size_t PENC_TOTAL = PENC_END - ZERO_END;

constexpr size_t OFF_X1 = PENC_END;                 // conv outputs / pooled
constexpr size_t OFF_P1 = OFF_X1 + (size_t)N0 * 32;
constexpr size_t OFF_X2 = OFF_P1 + (size_t)N1 * 32;
constexpr size_t OFF_P2 = OFF_X2 + (size_t)N1 * 64;
constexpr size_t OFF_X3 = OFF_P2 + (size_t)N2 * 64;
constexpr size_t OFF_P3 = OFF_X3 + (size_t)N2 * 64;
constexpr size_t OFF_X4 = OFF_P3 + (size_t)N3 * 64;
constexpr size_t OFF_P4 = OFF_X4 + (size_t)N3 * 128;
constexpr size_t OFF_FC1 = OFF_P4 + (size_t)NV * 128;
constexpr size_t WS_FLOATS = OFF_FC1 + (size_t)BB * 256;

// ---------------- helpers ----------------
__device__ __forceinline__ float eluf(float x) { return x > 0.f ? x : expm1f(x); }

// order-preserving float->uint map (monotone for all non-NaN floats)
__device__ __forceinline__ unsigned enc_f(float x) {
    unsigned u = __float_as_uint(x);
    return (u & 0x80000000u) ? ~u : (u | 0x80000000u);
}
__device__ __forceinline__ float dec_f(unsigned u) {
    u = (u & 0x80000000u) ? (u & 0x7fffffffu) : ~u;
    return __uint_as_float(u);
}

__global__ void init_enc(unsigned* __restrict__ p, int n) {
    int g = blockIdx.x * blockDim.x + threadIdx.x;
    if (g < n) p[g] = 0x007FFFFFu;   // enc(-inf)
}

// ---------------- spline conv: per-edge accumulate ----------------
template <int IN, int OUT>
__global__ void spline_edge(const float* __restrict__ x,
                            const float* __restrict__ pseudo,
                            const float* __restrict__ W,
                            const int* __restrict__ src,
                            const int* __restrict__ dst,
                            float* __restrict__ agg,
                            float* __restrict__ deg,
                            int E) {
    long long g = (long long)blockIdx.x * blockDim.x + threadIdx.x;
    int e = (int)(g / OUT);
    int o = (int)(g % OUT);
    if (e >= E) return;

    float v0 = pseudo[e * 3 + 0] * (KK - 1);
    float v1 = pseudo[e * 3 + 1] * (KK - 1);
    float v2 = pseudo[e * 3 + 2] * (KK - 1);
    float f0 = fminf(fmaxf(floorf(v0), 0.f), (float)(KK - 2));
    float f1 = fminf(fmaxf(floorf(v1), 0.f), (float)(KK - 2));
    float f2 = fminf(fmaxf(floorf(v2), 0.f), (float)(KK - 2));
    int lo0 = (int)f0, lo1 = (int)f1, lo2 = (int)f2;
    float fr0 = v0 - f0, fr1 = v1 - f1, fr2 = v2 - f2;

    int s = src[e], dn = dst[e];
    const float* xp = x + (size_t)s * IN;

    float acc = 0.f;
#pragma unroll
    for (int c = 0; c < 8; ++c) {
        int b0 = c & 1, b1 = (c >> 1) & 1, b2 = (c >> 2) & 1;
        int ki = (lo0 + b0) + (lo1 + b1) * KK + (lo2 + b2) * KK * KK;
        float bas = (b0 ? fr0 : 1.f - fr0) * (b1 ? fr1 : 1.f - fr1) * (b2 ? fr2 : 1.f - fr2);
        const float* Wp = W + (size_t)ki * IN * OUT + o;
        float sacc = 0.f;
        for (int i = 0; i < IN; ++i)
            sacc = fmaf(xp[i], Wp[(size_t)i * OUT], sacc);
        acc = fmaf(bas, sacc, acc);
    }
    atomicAdd(&agg[(size_t)dn * OUT + o], acc);
    if (o == 0) atomicAdd(&deg[dn], 1.f);
}

// ---------------- node finish: mean + root + bias + ELU ----------------
template <int IN, int OUT>
__global__ void node_finish(const float* __restrict__ agg,
                            const float* __restrict__ deg,
                            const float* __restrict__ x,
                            const float* __restrict__ root,
                            const float* __restrict__ bias,
                            float* __restrict__ out, int N) {
    int g = blockIdx.x * blockDim.x + threadIdx.x;
    if (g >= N * OUT) return;
    int n = g / OUT, o = g % OUT;
    float r = 0.f;
    for (int i = 0; i < IN; ++i)
        r = fmaf(x[(size_t)n * IN + i], root[(size_t)i * OUT + o], r);
    float dg = fmaxf(deg[n], 1.f);
    float val = agg[g] / dg + r + bias[o];
    out[g] = eluf(val);
}

// ---------------- max pool ----------------
template <int C>
__global__ void pool_scatter(const float* __restrict__ x,
                             const int* __restrict__ cluster,
                             unsigned* __restrict__ penc, int N) {
    int g = blockIdx.x * blockDim.x + threadIdx.x;
    if (g >= N * C) return;
    int n = g / C, c = g % C;
    atomicMax(&penc[(size_t)cluster[n] * C + c], enc_f(x[g]));
}

__global__ void pool_final(const unsigned* __restrict__ penc,
                           float* __restrict__ out, int M) {
    int g = blockIdx.x * blockDim.x + threadIdx.x;
    if (g >= M) return;
    float v = dec_f(penc[g]);
    out[g] = isfinite(v) ? v : 0.f;
}

// ---------------- FC head ----------------
__global__ void fc1_kernel(const float* __restrict__ xin,
                           const float* __restrict__ w,
                           const float* __restrict__ b,
                           float* __restrict__ out) {
    int bq = blockIdx.x;        // batch row (16)
    int p = threadIdx.x;        // 256 outputs
    const float* xr = xin + (size_t)bq * 1024;
    float acc = b[p];
    for (int q = 0; q < 1024; ++q)
        acc = fmaf(xr[q], w[(size_t)q * 256 + p], acc);
    out[(size_t)bq * 256 + p] = eluf(acc);
}

__global__ void fc2_ls_kernel(const float* __restrict__ xin,
                              const float* __restrict__ w,
                              const float* __restrict__ b,
                              float* __restrict__ out) {
    __shared__ float l[10];
    __shared__ float red[2];
    int bq = blockIdx.x;
    int t = threadIdx.x;        // 64
    if (t < 10) {
        const float* xr = xin + (size_t)bq * 256;
        float acc = b[t];
        for (int q = 0; q < 256; ++q)
            acc = fmaf(xr[q], w[(size_t)q * 10 + t], acc);
        l[t] = acc;
    }
    __syncthreads();
    if (t == 0) {
        float m = l[0];
        for (int i = 1; i < 10; ++i) m = fmaxf(m, l[i]);
        float s = 0.f;
        for (int i = 0; i < 10; ++i) s += expf(l[i] - m);
        red[0] = m;
        red[1] = logf(s);
    }
    __syncthreads();
    if (t < 10) out[(size_t)bq * 10 + t] = l[t] - red[0] - red[1];
}

inline unsigned blk(long long t) { return (unsigned)((t + 255) / 256); }

} // namespace

extern "C" void kernel_launch(void* const* d_in, const int* in_sizes, int n_in,
                              void* d_out, int out_size, void* d_ws, size_t ws_size,
                              hipStream_t stream) {
    const float* x0    = (const float*)d_in[0];
    const float* ps0   = (const float*)d_in[1];
    const float* ps1   = (const float*)d_in[2];
    const float* ps2   = (const float*)d_in[3];
    const float* ps3   = (const float*)d_in[4];
    const float* W1    = (const float*)d_in[5];
    const float* root1 = (const float*)d_in[6];
    const float* b1    = (const float*)d_in[7];
    const float* W2    = (const float*)d_in[8];
    const float* root2 = (const float*)d_in[9];
    const float* b2    = (const float*)d_in[10];
    const float* W3    = (const float*)d_in[11];
    const float* root3 = (const float*)d_in[12];
    const float* b3    = (const float*)d_in[13];
    const float* W4    = (const float*)d_in[14];
    const float* root4 = (const float*)d_in[15];
    const float* b4    = (const float*)d_in[16];
    const float* fc1w  = (const float*)d_in[17];
    const float* fc1b  = (const float*)d_in[18];
    const float* fc2w  = (const float*)d_in[19];
    const float* fc2b  = (const float*)d_in[20];
    const int* src0 = (const int*)d_in[21];
    const int* dst0 = (const int*)d_in[22];
    const int* src1 = (const int*)d_in[23];
    const int* dst1 = (const int*)d_in[24];
    const int* src2 = (const int*)d_in[25];
    const int* dst2 = (const int*)d_in[26];
    const int* src3 = (const int*)d_in[27];
    const int* dst3 = (const int*)d_in[28];
    const int* cl0  = (const int*)d_in[29];
    const int* cl1  = (const int*)d_in[30];
    const int* cl2  = (const int*)d_in[31];
    const int* cl3  = (const int*)d_in[32];

    float* ws = (float*)d_ws;
    float* out = (float*)d_out;

    // zero accumulators + degree counters
    hipMemsetAsync(ws + OFF_AGG1, 0, ZERO_END * sizeof(float), stream);
    // init pool-max encoded buffers to enc(-inf)
    init_enc<<<blk(PENC_TOTAL), 256, 0, stream>>>((unsigned*)(ws + OFF_PENC1), (int)PENC_TOTAL);

    // ---- layer 1: conv(1->32) on N0, pool -> N1 ----
    spline_edge<1, 32><<<blk((long long)E0 * 32), 256, 0, stream>>>(
        x0, ps0, W1, src0, dst0, ws + OFF_AGG1, ws + OFF_DEG1, E0);
    node_finish<1, 32><<<blk((long long)N0 * 32), 256, 0, stream>>>(
        ws + OFF_AGG1, ws + OFF_DEG1, x0, root1, b1, ws + OFF_X1, N0);
    pool_scatter<32><<<blk((long long)N0 * 32), 256, 0, stream>>>(
        ws + OFF_X1, cl0, (unsigned*)(ws + OFF_PENC1), N0);
    pool_final<<<blk((long long)N1 * 32), 256, 0, stream>>>(
        (unsigned*)(ws + OFF_PENC1), ws + OFF_P1, N1 * 32);

    // ---- layer 2: conv(32->64) on N1, pool -> N2 ----
    spline_edge<32, 64><<<blk((long long)E1 * 64), 256, 0, stream>>>(
        ws + OFF_P1, ps1, W2, src1, dst1, ws + OFF_AGG2, ws + OFF_DEG2, E1);
    node_finish<32, 64><<<blk((long long)N1 * 64), 256, 0, stream>>>(
        ws + OFF_AGG2, ws + OFF_DEG2, ws + OFF_P1, root2, b2, ws + OFF_X2, N1);
    pool_scatter<64><<<blk((long long)N1 * 64), 256, 0, stream>>>(
        ws + OFF_X2, cl1, (unsigned*)(ws + OFF_PENC2), N1);
    pool_final<<<blk((long long)N2 * 64), 256, 0, stream>>>(
        (unsigned*)(ws + OFF_PENC2), ws + OFF_P2, N2 * 64);

    // ---- layer 3: conv(64->64) on N2, pool -> N3 ----
    spline_edge<64, 64><<<blk((long long)E2 * 64), 256, 0, stream>>>(
        ws + OFF_P2, ps2, W3, src2, dst2, ws + OFF_AGG3, ws + OFF_DEG3, E2);
    node_finish<64, 64><<<blk((long long)N2 * 64), 256, 0, stream>>>(
        ws + OFF_AGG3, ws + OFF_DEG3, ws + OFF_P2, root3, b3, ws + OFF_X3, N2);
    pool_scatter<64><<<blk((long long)N2 * 64), 256, 0, stream>>>(
        ws + OFF_X3, cl2, (unsigned*)(ws + OFF_PENC3), N2);
    pool_final<<<blk((long long)N3 * 64), 256, 0, stream>>>(
        (unsigned*)(ws + OFF_PENC3), ws + OFF_P3, N3 * 64);

    // ---- layer 4: conv(64->128) on N3, pool -> V=128 ----
    spline_edge<64, 128><<<blk((long long)E3 * 128), 256, 0, stream>>>(
        ws + OFF_P3, ps3, W4, src3, dst3, ws + OFF_AGG4, ws + OFF_DEG4, E3);
    node_finish<64, 128><<<blk((long long)N3 * 128), 256, 0, stream>>>(
        ws + OFF_AGG4, ws + OFF_DEG4, ws + OFF_P3, root4, b4, ws + OFF_X4, N3);
    pool_scatter<128><<<blk((long long)N3 * 128), 256, 0, stream>>>(
        ws + OFF_X4, cl3, (unsigned*)(ws + OFF_PENC4), N3);
    pool_final<<<blk((long long)NV * 128), 256, 0, stream>>>(
        (unsigned*)(ws + OFF_PENC4), ws + OFF_P4, NV * 128);

    // ---- FC head ----
    fc1_kernel<<<16, 256, 0, stream>>>(ws + OFF_P4, fc1w, fc1b, ws + OFF_FC1);
    fc2_ls_kernel<<<16, 64, 0, stream>>>(ws + OFF_FC1, fc2w, fc2b, out);
}

// Round 2
// 380.694 us; speedup vs baseline: 1.4933x; 1.4933x over previous
//
#include <hip/hip_runtime.h>
#include <hip/hip_bf16.h>
#include <math.h>

namespace {

constexpr int KK = 5;
constexpr int K3 = 125;
constexpr int N0 = 16384, E0 = 262144;
constexpr int N1 = 4096,  E1 = 65536;
constexpr int N2 = 1024,  E2 = 16384;
constexpr int N3 = 256,   E3 = 4096;
constexpr int NV = 128;            // B*8 final "nodes"
constexpr int BB = 16;

// ---------------- workspace layout (float offsets) ----------------
constexpr size_t OFF_AGG1 = 0;
constexpr size_t OFF_AGG2 = OFF_AGG1 + (size_t)N0 * 32;
constexpr size_t OFF_AGG3 = OFF_AGG2 + (size_t)N1 * 64;
constexpr size_t OFF_AGG4 = OFF_AGG3 + (size_t)N2 * 64;
constexpr size_t OFF_DEG1 = OFF_AGG4 + (size_t)N3 * 128;
constexpr size_t OFF_DEG2 = OFF_DEG1 + N0;
constexpr size_t OFF_DEG3 = OFF_DEG2 + N1;
constexpr size_t OFF_DEG4 = OFF_DEG3 + N2;
constexpr size_t ZERO_END = OFF_DEG4 + N3;          // region zeroed each call

constexpr size_t OFF_PENC1 = ZERO_END;              // encoded-max pool buffers
constexpr size_t OFF_PENC2 = OFF_PENC1 + (size_t)N1 * 32;
constexpr size_t OFF_PENC3 = OFF_PENC2 + (size_t)N2 * 64;
constexpr size_t OFF_PENC4 = OFF_PENC3 + (size_t)N3 * 64;
constexpr size_t PENC_END  = OFF_PENC4 + (size_t)NV * 128;
constexpr size_t PENC_TOTAL = PENC_END - ZERO_END;

constexpr size_t OFF_X1 = PENC_END;                 // conv outputs / pooled
constexpr size_t OFF_P1 = OFF_X1 + (size_t)N0 * 32;
constexpr size_t OFF_X2 = OFF_P1 + (size_t)N1 * 32;
constexpr size_t OFF_P2 = OFF_X2 + (size_t)N1 * 64;
constexpr size_t OFF_X3 = OFF_P2 + (size_t)N2 * 64;
constexpr size_t OFF_P3 = OFF_X3 + (size_t)N2 * 64;
constexpr size_t OFF_X4 = OFF_P3 + (size_t)N3 * 64;
constexpr size_t OFF_P4 = OFF_X4 + (size_t)N3 * 128;
constexpr size_t OFF_FC1 = OFF_P4 + (size_t)NV * 128;
constexpr size_t WS_FLOATS = OFF_FC1 + (size_t)BB * 256;

// y table (bf16, shared across layers 2-4); layer2 is largest: 4096*125*64
constexpr size_t OFF_Y = WS_FLOATS;
constexpr size_t Y_ELEMS_MAX = (size_t)N1 * K3 * 64;   // 32.768M bf16 = 65.5MB
constexpr size_t WS_NEED_BYTES = OFF_Y * 4 + Y_ELEMS_MAX * 2;

// ---------------- helpers ----------------
__device__ __forceinline__ float eluf(float x) { return x > 0.f ? x : expm1f(x); }

__device__ __forceinline__ unsigned enc_f(float x) {
    unsigned u = __float_as_uint(x);
    return (u & 0x80000000u) ? ~u : (u | 0x80000000u);
}
__device__ __forceinline__ float dec_f(unsigned u) {
    u = (u & 0x80000000u) ? (u & 0x7fffffffu) : ~u;
    return __uint_as_float(u);
}

// decode pseudo -> 8 corner weights + kernel indices (matches reference math)
__device__ __forceinline__ void decode_edge(const float* __restrict__ pseudo, int e,
                                            float bas[8], int kid[8]) {
    float v0 = pseudo[e * 3 + 0] * (KK - 1);
    float v1 = pseudo[e * 3 + 1] * (KK - 1);
    float v2 = pseudo[e * 3 + 2] * (KK - 1);
    float f0 = fminf(fmaxf(floorf(v0), 0.f), (float)(KK - 2));
    float f1 = fminf(fmaxf(floorf(v1), 0.f), (float)(KK - 2));
    float f2 = fminf(fmaxf(floorf(v2), 0.f), (float)(KK - 2));
    int lo0 = (int)f0, lo1 = (int)f1, lo2 = (int)f2;
    float fr0 = v0 - f0, fr1 = v1 - f1, fr2 = v2 - f2;
#pragma unroll
    for (int c = 0; c < 8; ++c) {
        int b0 = c & 1, b1 = (c >> 1) & 1, b2 = (c >> 2) & 1;
        kid[c] = (lo0 + b0) + (lo1 + b1) * KK + (lo2 + b2) * KK * KK;
        bas[c] = (b0 ? fr0 : 1.f - fr0) * (b1 ? fr1 : 1.f - fr1) * (b2 ? fr2 : 1.f - fr2);
    }
}

__global__ void init_enc(unsigned* __restrict__ p, int n) {
    int g = blockIdx.x * blockDim.x + threadIdx.x;
    if (g < n) p[g] = 0x007FFFFFu;   // enc(-inf)
}

// ---------------- layer 1 special case: IN=1, W1 in LDS ----------------
__global__ void spline_l1(const float* __restrict__ x,
                          const float* __restrict__ pseudo,
                          const float* __restrict__ W1,
                          const int* __restrict__ src,
                          const int* __restrict__ dst,
                          float* __restrict__ agg,
                          float* __restrict__ deg, int E) {
    __shared__ float wlds[K3 * 32];
    int tid = threadIdx.x;
    for (int i = tid; i < K3 * 32; i += 256) wlds[i] = W1[i];
    __syncthreads();
    int o = tid & 31;
    int esub = tid >> 5;                 // 0..7
    int ebase = blockIdx.x * 32 + esub;
#pragma unroll
    for (int r = 0; r < 4; ++r) {
        int e = ebase + r * 8;
        if (e >= E) continue;
        float bas[8]; int kid[8];
        decode_edge(pseudo, e, bas, kid);
        int s = src[e], dn = dst[e];
        float xv = x[s];
        float acc = 0.f;
#pragma unroll
        for (int c = 0; c < 8; ++c)
            acc = fmaf(bas[c], wlds[kid[c] * 32 + o], acc);
        atomicAdd(&agg[(size_t)dn * 32 + o], xv * acc);
        if (o == 0) atomicAdd(&deg[dn], 1.f);
    }
}

// ---------------- dense precompute y[n,k,o] = x @ W (bf16 out) ----------------
template <int IN, int OUT>
__global__ void gemm_y(const float* __restrict__ x,
                       const float* __restrict__ W,
                       __hip_bfloat16* __restrict__ y, int N) {
    constexpr int KO = K3 * OUT;
    __shared__ float xs[32][IN];
    int kt = blockIdx.x % (KO / 64);
    int n0 = (blockIdx.x / (KO / 64)) * 32;
    int tid = threadIdx.x;
    for (int idx = tid; idx < 32 * IN; idx += 256)
        xs[idx / IN][idx % IN] = x[(size_t)(n0 + idx / IN) * IN + idx % IN];
    __syncthreads();
    int col = kt * 64 + (tid & 63);
    int nsub = tid >> 6;                 // 0..3 (wave id)
    int k = col / OUT, o = col % OUT;
    const float* Wp = W + (size_t)k * IN * OUT + o;
    float acc[8] = {0.f, 0.f, 0.f, 0.f, 0.f, 0.f, 0.f, 0.f};
#pragma unroll 4
    for (int i = 0; i < IN; ++i) {
        float w = Wp[(size_t)i * OUT];
#pragma unroll
        for (int j = 0; j < 8; ++j)
            acc[j] = fmaf(xs[nsub * 8 + j][i], w, acc[j]);
    }
#pragma unroll
    for (int j = 0; j < 8; ++j)
        y[(size_t)(n0 + nsub * 8 + j) * KO + col] = __float2bfloat16(acc[j]);
}

// ---------------- per-edge gather from y table ----------------
template <int OUT>
__global__ void gather_edge(const __hip_bfloat16* __restrict__ y,
                            const float* __restrict__ pseudo,
                            const int* __restrict__ src,
                            const int* __restrict__ dst,
                            float* __restrict__ agg,
                            float* __restrict__ deg, int E) {
    long long g = (long long)blockIdx.x * blockDim.x + threadIdx.x;
    int e = (int)(g / OUT);
    int o = (int)(g % OUT);
    if (e >= E) return;
    float bas[8]; int kid[8];
    decode_edge(pseudo, e, bas, kid);
    int s = src[e], dn = dst[e];
    const __hip_bfloat16* yp = y + (size_t)s * (K3 * OUT) + o;
    float acc = 0.f;
#pragma unroll
    for (int c = 0; c < 8; ++c)
        acc = fmaf(bas[c], __bfloat162float(yp[(size_t)kid[c] * OUT]), acc);
    atomicAdd(&agg[(size_t)dn * OUT + o], acc);
    if (o == 0) atomicAdd(&deg[dn], 1.f);
}

// ---------------- fallback per-edge (used only if ws too small) ----------------
template <int IN, int OUT>
__global__ void spline_edge(const float* __restrict__ x,
                            const float* __restrict__ pseudo,
                            const float* __restrict__ W,
                            const int* __restrict__ src,
                            const int* __restrict__ dst,
                            float* __restrict__ agg,
                            float* __restrict__ deg, int E) {
    long long g = (long long)blockIdx.x * blockDim.x + threadIdx.x;
    int e = (int)(g / OUT);
    int o = (int)(g % OUT);
    if (e >= E) return;
    float bas[8]; int kid[8];
    decode_edge(pseudo, e, bas, kid);
    int s = src[e], dn = dst[e];
    const float* xp = x + (size_t)s * IN;
    float acc = 0.f;
#pragma unroll
    for (int c = 0; c < 8; ++c) {
        const float* Wp = W + (size_t)kid[c] * IN * OUT + o;
        float sacc = 0.f;
        for (int i = 0; i < IN; ++i)
            sacc = fmaf(xp[i], Wp[(size_t)i * OUT], sacc);
        acc = fmaf(bas[c], sacc, acc);
    }
    atomicAdd(&agg[(size_t)dn * OUT + o], acc);
    if (o == 0) atomicAdd(&deg[dn], 1.f);
}

// ---------------- node finish: mean + root + bias + ELU ----------------
template <int IN, int OUT>
__global__ void node_finish(const float* __restrict__ agg,
                            const float* __restrict__ deg,
                            const float* __restrict__ x,
                            const float* __restrict__ root,
                            const float* __restrict__ bias,
                            float* __restrict__ out, int N) {
    int g = blockIdx.x * blockDim.x + threadIdx.x;
    if (g >= N * OUT) return;
    int n = g / OUT, o = g % OUT;
    float r = 0.f;
    for (int i = 0; i < IN; ++i)
        r = fmaf(x[(size_t)n * IN + i], root[(size_t)i * OUT + o], r);
    float dg = fmaxf(deg[n], 1.f);
    float val = agg[g] / dg + r + bias[o];
    out[g] = eluf(val);
}

// ---------------- max pool ----------------
template <int C>
__global__ void pool_scatter(const float* __restrict__ x,
                             const int* __restrict__ cluster,
                             unsigned* __restrict__ penc, int N) {
    int g = blockIdx.x * blockDim.x + threadIdx.x;
    if (g >= N * C) return;
    int n = g / C, c = g % C;
    atomicMax(&penc[(size_t)cluster[n] * C + c], enc_f(x[g]));
}

__global__ void pool_final(const unsigned* __restrict__ penc,
                           float* __restrict__ out, int M) {
    int g = blockIdx.x * blockDim.x + threadIdx.x;
    if (g >= M) return;
    float v = dec_f(penc[g]);
    out[g] = isfinite(v) ? v : 0.f;
}

// ---------------- FC head ----------------
__global__ void fc1_kernel(const float* __restrict__ xin,
                           const float* __restrict__ w,
                           const float* __restrict__ b,
                           float* __restrict__ out) {
    int bq = blockIdx.x;        // batch row (16)
    int p = threadIdx.x;        // 256 outputs
    const float* xr = xin + (size_t)bq * 1024;
    float acc = b[p];
    for (int q = 0; q < 1024; ++q)
        acc = fmaf(xr[q], w[(size_t)q * 256 + p], acc);
    out[(size_t)bq * 256 + p] = eluf(acc);
}

__global__ void fc2_ls_kernel(const float* __restrict__ xin,
                              const float* __restrict__ w,
                              const float* __restrict__ b,
                              float* __restrict__ out) {
    __shared__ float l[10];
    __shared__ float red[2];
    int bq = blockIdx.x;
    int t = threadIdx.x;        // 64
    if (t < 10) {
        const float* xr = xin + (size_t)bq * 256;
        float acc = b[t];
        for (int q = 0; q < 256; ++q)
            acc = fmaf(xr[q], w[(size_t)q * 10 + t], acc);
        l[t] = acc;
    }
    __syncthreads();
    if (t == 0) {
        float m = l[0];
        for (int i = 1; i < 10; ++i) m = fmaxf(m, l[i]);
        float s = 0.f;
        for (int i = 0; i < 10; ++i) s += expf(l[i] - m);
        red[0] = m;
        red[1] = logf(s);
    }
    __syncthreads();
    if (t < 10) out[(size_t)bq * 10 + t] = l[t] - red[0] - red[1];
}

inline unsigned blk(long long t) { return (unsigned)((t + 255) / 256); }

} // namespace

extern "C" void kernel_launch(void* const* d_in, const int* in_sizes, int n_in,
                              void* d_out, int out_size, void* d_ws, size_t ws_size,
                              hipStream_t stream) {
    const float* x0    = (const float*)d_in[0];
    const float* ps0   = (const float*)d_in[1];
    const float* ps1   = (const float*)d_in[2];
    const float* ps2   = (const float*)d_in[3];
    const float* ps3   = (const float*)d_in[4];
    const float* W1    = (const float*)d_in[5];
    const float* root1 = (const float*)d_in[6];
    const float* b1    = (const float*)d_in[7];
    const float* W2    = (const float*)d_in[8];
    const float* root2 = (const float*)d_in[9];
    const float* b2    = (const float*)d_in[10];
    const float* W3    = (const float*)d_in[11];
    const float* root3 = (const float*)d_in[12];
    const float* b3    = (const float*)d_in[13];
    const float* W4    = (const float*)d_in[14];
    const float* root4 = (const float*)d_in[15];
    const float* b4    = (const float*)d_in[16];
    const float* fc1w  = (const float*)d_in[17];
    const float* fc1b  = (const float*)d_in[18];
    const float* fc2w  = (const float*)d_in[19];
    const float* fc2b  = (const float*)d_in[20];
    const int* src0 = (const int*)d_in[21];
    const int* dst0 = (const int*)d_in[22];
    const int* src1 = (const int*)d_in[23];
    const int* dst1 = (const int*)d_in[24];
    const int* src2 = (const int*)d_in[25];
    const int* dst2 = (const int*)d_in[26];
    const int* src3 = (const int*)d_in[27];
    const int* dst3 = (const int*)d_in[28];
    const int* cl0  = (const int*)d_in[29];
    const int* cl1  = (const int*)d_in[30];
    const int* cl2  = (const int*)d_in[31];
    const int* cl3  = (const int*)d_in[32];

    float* ws = (float*)d_ws;
    float* out = (float*)d_out;
    __hip_bfloat16* yb = (__hip_bfloat16*)(ws + OFF_Y);
    const bool use_y = (ws_size >= WS_NEED_BYTES);

    // zero accumulators + degree counters
    hipMemsetAsync(ws + OFF_AGG1, 0, ZERO_END * sizeof(float), stream);
    // init pool-max encoded buffers to enc(-inf)
    init_enc<<<blk(PENC_TOTAL), 256, 0, stream>>>((unsigned*)(ws + OFF_PENC1), (int)PENC_TOTAL);

    // ---- layer 1: conv(1->32) on N0, pool -> N1 ----
    spline_l1<<<E0 / 32, 256, 0, stream>>>(x0, ps0, W1, src0, dst0,
                                           ws + OFF_AGG1, ws + OFF_DEG1, E0);
    node_finish<1, 32><<<blk((long long)N0 * 32), 256, 0, stream>>>(
        ws + OFF_AGG1, ws + OFF_DEG1, x0, root1, b1, ws + OFF_X1, N0);
    pool_scatter<32><<<blk((long long)N0 * 32), 256, 0, stream>>>(
        ws + OFF_X1, cl0, (unsigned*)(ws + OFF_PENC1), N0);
    pool_final<<<blk((long long)N1 * 32), 256, 0, stream>>>(
        (unsigned*)(ws + OFF_PENC1), ws + OFF_P1, N1 * 32);

    // ---- layer 2: conv(32->64) on N1, pool -> N2 ----
    if (use_y) {
        gemm_y<32, 64><<<(N1 / 32) * (K3 * 64 / 64), 256, 0, stream>>>(ws + OFF_P1, W2, yb, N1);
        gather_edge<64><<<blk((long long)E1 * 64), 256, 0, stream>>>(
            yb, ps1, src1, dst1, ws + OFF_AGG2, ws + OFF_DEG2, E1);
    } else {
        spline_edge<32, 64><<<blk((long long)E1 * 64), 256, 0, stream>>>(
            ws + OFF_P1, ps1, W2, src1, dst1, ws + OFF_AGG2, ws + OFF_DEG2, E1);
    }
    node_finish<32, 64><<<blk((long long)N1 * 64), 256, 0, stream>>>(
        ws + OFF_AGG2, ws + OFF_DEG2, ws + OFF_P1, root2, b2, ws + OFF_X2, N1);
    pool_scatter<64><<<blk((long long)N1 * 64), 256, 0, stream>>>(
        ws + OFF_X2, cl1, (unsigned*)(ws + OFF_PENC2), N1);
    pool_final<<<blk((long long)N2 * 64), 256, 0, stream>>>(
        (unsigned*)(ws + OFF_PENC2), ws + OFF_P2, N2 * 64);

    // ---- layer 3: conv(64->64) on N2, pool -> N3 ----
    if (use_y) {
        gemm_y<64, 64><<<(N2 / 32) * (K3 * 64 / 64), 256, 0, stream>>>(ws + OFF_P2, W3, yb, N2);
        gather_edge<64><<<blk((long long)E2 * 64), 256, 0, stream>>>(
            yb, ps2, src2, dst2, ws + OFF_AGG3, ws + OFF_DEG3, E2);
    } else {
        spline_edge<64, 64><<<blk((long long)E2 * 64), 256, 0, stream>>>(
            ws + OFF_P2, ps2, W3, src2, dst2, ws + OFF_AGG3, ws + OFF_DEG3, E2);
    }
    node_finish<64, 64><<<blk((long long)N2 * 64), 256, 0, stream>>>(
        ws + OFF_AGG3, ws + OFF_DEG3, ws + OFF_P2, root3, b3, ws + OFF_X3, N2);
    pool_scatter<64><<<blk((long long)N2 * 64), 256, 0, stream>>>(
        ws + OFF_X3, cl2, (unsigned*)(ws + OFF_PENC3), N2);
    pool_final<<<blk((long long)N3 * 64), 256, 0, stream>>>(
        (unsigned*)(ws + OFF_PENC3), ws + OFF_P3, N3 * 64);

    // ---- layer 4: conv(64->128) on N3, pool -> V=128 ----
    if (use_y) {
        gemm_y<64, 128><<<(N3 / 32) * (K3 * 128 / 64), 256, 0, stream>>>(ws + OFF_P3, W4, yb, N3);
        gather_edge<128><<<blk((long long)E3 * 128), 256, 0, stream>>>(
            yb, ps3, src3, dst3, ws + OFF_AGG4, ws + OFF_DEG4, E3);
    } else {
        spline_edge<64, 128><<<blk((long long)E3 * 128), 256, 0, stream>>>(
            ws + OFF_P3, ps3, W4, src3, dst3, ws + OFF_AGG4, ws + OFF_DEG4, E3);
    }
    node_finish<64, 128><<<blk((long long)N3 * 128), 256, 0, stream>>>(
        ws + OFF_AGG4, ws + OFF_DEG4, ws + OFF_P3, root4, b4, ws + OFF_X4, N3);
    pool_scatter<128><<<blk((long long)N3 * 128), 256, 0, stream>>>(
        ws + OFF_X4, cl3, (unsigned*)(ws + OFF_PENC4), N3);
    pool_final<<<blk((long long)NV * 128), 256, 0, stream>>>(
        (unsigned*)(ws + OFF_PENC4), ws + OFF_P4, NV * 128);

    // ---- FC head ----
    fc1_kernel<<<16, 256, 0, stream>>>(ws + OFF_P4, fc1w, fc1b, ws + OFF_FC1);
    fc2_ls_kernel<<<16, 64, 0, stream>>>(ws + OFF_FC1, fc2w, fc2b, out);
}

// Round 3
// 371.381 us; speedup vs baseline: 1.5308x; 1.0251x over previous
//
#include <hip/hip_runtime.h>
#include <hip/hip_bf16.h>
#include <math.h>

namespace {

typedef unsigned long long u64;
typedef __attribute__((ext_vector_type(8))) short bf16x8;
typedef __attribute__((ext_vector_type(4))) float f32x4;

constexpr int KK = 5;
constexpr int K3 = 125;
constexpr int N0 = 16384, E0 = 262144;
constexpr int N1 = 4096,  E1 = 65536;
constexpr int N2 = 1024,  E2 = 16384;
constexpr int N3 = 256,   E3 = 4096;
constexpr int NV = 128;            // B*8 final "nodes"
constexpr int BB = 16;

// ---------------- workspace layout (float offsets) ----------------
constexpr size_t OFF_AGG1 = 0;
constexpr size_t OFF_AGG2 = OFF_AGG1 + (size_t)N0 * 32;
constexpr size_t OFF_AGG3 = OFF_AGG2 + (size_t)N1 * 64;
constexpr size_t OFF_AGG4 = OFF_AGG3 + (size_t)N2 * 64;
constexpr size_t OFF_DEG1 = OFF_AGG4 + (size_t)N3 * 128;
constexpr size_t OFF_DEG2 = OFF_DEG1 + N0;
constexpr size_t OFF_DEG3 = OFF_DEG2 + N1;
constexpr size_t OFF_DEG4 = OFF_DEG3 + N2;
constexpr size_t ZERO_END = OFF_DEG4 + N3;          // region zeroed each call

constexpr size_t OFF_PENC1 = ZERO_END;              // encoded-max pool buffers
constexpr size_t OFF_PENC2 = OFF_PENC1 + (size_t)N1 * 32;
constexpr size_t OFF_PENC3 = OFF_PENC2 + (size_t)N2 * 64;
constexpr size_t OFF_PENC4 = OFF_PENC3 + (size_t)N3 * 64;
constexpr size_t PENC_END  = OFF_PENC4 + (size_t)NV * 128;
constexpr size_t PENC_TOTAL = PENC_END - ZERO_END;

constexpr size_t OFF_X1 = PENC_END;                 // conv outputs / pooled
constexpr size_t OFF_P1 = OFF_X1 + (size_t)N0 * 32;
constexpr size_t OFF_X2 = OFF_P1 + (size_t)N1 * 32;
constexpr size_t OFF_P2 = OFF_X2 + (size_t)N1 * 64;
constexpr size_t OFF_X3 = OFF_P2 + (size_t)N2 * 64;
constexpr size_t OFF_P3 = OFF_X3 + (size_t)N2 * 64;
constexpr size_t OFF_X4 = OFF_P3 + (size_t)N3 * 64;
constexpr size_t OFF_P4 = OFF_X4 + (size_t)N3 * 128;
constexpr size_t OFF_FC1 = OFF_P4 + (size_t)NV * 128;
constexpr size_t WS_FLOATS = OFF_FC1 + (size_t)BB * 256;

// basis/kid tables (shared, sized for E0)
constexpr size_t OFF_BAS = WS_FLOATS;                    // E0 * 8 f32
constexpr size_t OFF_KID = OFF_BAS + (size_t)E0 * 8;     // E0 u64 (2 floats each)
constexpr size_t TAB_END = OFF_KID + (size_t)E0 * 2;
// bf16 buffers
constexpr size_t OFF_XB  = TAB_END;                      // up to N1*32 bf16
constexpr size_t OFF_WT  = OFF_XB + (size_t)N1 * 32 / 2; // up to 16000*64 bf16
constexpr size_t OFF_Y   = OFF_WT + (size_t)16000 * 64 / 2;
constexpr size_t Y_FLOATS = (size_t)N1 * K3 * 64 / 2;    // largest y: 4096x8000 bf16
constexpr size_t WS_END  = OFF_Y + Y_FLOATS;

constexpr size_t WS_NEED_TAB = TAB_END * sizeof(float);
constexpr size_t WS_NEED_Y   = WS_END * sizeof(float);

// ---------------- helpers ----------------
__device__ __forceinline__ float eluf(float x) { return x > 0.f ? x : expm1f(x); }

__device__ __forceinline__ unsigned enc_f(float x) {
    unsigned u = __float_as_uint(x);
    return (u & 0x80000000u) ? ~u : (u | 0x80000000u);
}
__device__ __forceinline__ float dec_f(unsigned u) {
    u = (u & 0x80000000u) ? (u & 0x7fffffffu) : ~u;
    return __uint_as_float(u);
}
__device__ __forceinline__ float bf2f(unsigned short u) {
    return __uint_as_float((unsigned)u << 16);
}
__device__ __forceinline__ unsigned short f2bf(float v) {
    __hip_bfloat16 h = __float2bfloat16(v);
    return *reinterpret_cast<unsigned short*>(&h);
}

// decode pseudo -> 8 corner weights + kernel indices (matches reference math)
__device__ __forceinline__ void decode_edge(const float* __restrict__ pseudo, int e,
                                            float bas[8], int kid[8]) {
    float v0 = pseudo[e * 3 + 0] * (KK - 1);
    float v1 = pseudo[e * 3 + 1] * (KK - 1);
    float v2 = pseudo[e * 3 + 2] * (KK - 1);
    float f0 = fminf(fmaxf(floorf(v0), 0.f), (float)(KK - 2));
    float f1 = fminf(fmaxf(floorf(v1), 0.f), (float)(KK - 2));
    float f2 = fminf(fmaxf(floorf(v2), 0.f), (float)(KK - 2));
    int lo0 = (int)f0, lo1 = (int)f1, lo2 = (int)f2;
    float fr0 = v0 - f0, fr1 = v1 - f1, fr2 = v2 - f2;
#pragma unroll
    for (int c = 0; c < 8; ++c) {
        int b0 = c & 1, b1 = (c >> 1) & 1, b2 = (c >> 2) & 1;
        kid[c] = (lo0 + b0) + (lo1 + b1) * KK + (lo2 + b2) * KK * KK;
        bas[c] = (b0 ? fr0 : 1.f - fr0) * (b1 ? fr1 : 1.f - fr1) * (b2 ? fr2 : 1.f - fr2);
    }
}

__global__ void init_enc(unsigned* __restrict__ p, int n) {
    int g = blockIdx.x * blockDim.x + threadIdx.x;
    if (g < n) p[g] = 0x007FFFFFu;   // enc(-inf)
}

// ---------------- per-edge basis/kid table ----------------
__global__ void decode_basis(const float* __restrict__ pseudo,
                             float* __restrict__ bas, u64* __restrict__ kid, int E) {
    int e = blockIdx.x * blockDim.x + threadIdx.x;
    if (e >= E) return;
    float b[8]; int k[8];
    decode_edge(pseudo, e, b, k);
    float4 q0 = make_float4(b[0], b[1], b[2], b[3]);
    float4 q1 = make_float4(b[4], b[5], b[6], b[7]);
    *(float4*)(bas + (size_t)e * 8) = q0;
    *(float4*)(bas + (size_t)e * 8 + 4) = q1;
    u64 p = 0;
#pragma unroll
    for (int c = 0; c < 8; ++c) p |= (u64)(unsigned)k[c] << (8 * c);
    kid[e] = p;
}

// ---------------- layer 1: IN=1, W1 in LDS, table-driven ----------------
__global__ void spline_l1_t(const float* __restrict__ x,
                            const float* __restrict__ bas,
                            const u64* __restrict__ kid,
                            const float* __restrict__ W1,
                            const int* __restrict__ src,
                            const int* __restrict__ dst,
                            float* __restrict__ agg,
                            float* __restrict__ deg, int E) {
    __shared__ float wlds[K3 * 32];
    int tid = threadIdx.x;
    for (int i = tid; i < K3 * 32; i += 256) wlds[i] = W1[i];
    __syncthreads();
    int o = tid & 31;
    int esub = tid >> 5;                 // 0..7
#pragma unroll
    for (int r = 0; r < 8; ++r) {
        int e = blockIdx.x * 64 + r * 8 + esub;
        if (e >= E) continue;
        float4 q0 = *(const float4*)(bas + (size_t)e * 8);
        float4 q1 = *(const float4*)(bas + (size_t)e * 8 + 4);
        float b[8] = {q0.x, q0.y, q0.z, q0.w, q1.x, q1.y, q1.z, q1.w};
        u64 k8 = kid[e];
        int s = src[e], dn = dst[e];
        float xv = x[s];
        float acc = 0.f;
#pragma unroll
        for (int c = 0; c < 8; ++c) {
            int kc = (int)((k8 >> (8 * c)) & 255u);
            acc = fmaf(b[c], wlds[kc * 32 + o], acc);
        }
        atomicAdd(&agg[(size_t)dn * 32 + o], xv * acc);
        if (o == 0) atomicAdd(&deg[dn], 1.f);
    }
}

// fallback layer-1 (inline decode) if ws too small for tables
__global__ void spline_l1(const float* __restrict__ x,
                          const float* __restrict__ pseudo,
                          const float* __restrict__ W1,
                          const int* __restrict__ src,
                          const int* __restrict__ dst,
                          float* __restrict__ agg,
                          float* __restrict__ deg, int E) {
    __shared__ float wlds[K3 * 32];
    int tid = threadIdx.x;
    for (int i = tid; i < K3 * 32; i += 256) wlds[i] = W1[i];
    __syncthreads();
    int o = tid & 31;
    int esub = tid >> 5;
#pragma unroll
    for (int r = 0; r < 4; ++r) {
        int e = blockIdx.x * 32 + r * 8 + esub;
        if (e >= E) continue;
        float bas[8]; int kidv[8];
        decode_edge(pseudo, e, bas, kidv);
        int s = src[e], dn = dst[e];
        float xv = x[s];
        float acc = 0.f;
#pragma unroll
        for (int c = 0; c < 8; ++c)
            acc = fmaf(bas[c], wlds[kidv[c] * 32 + o], acc);
        atomicAdd(&agg[(size_t)dn * 32 + o], xv * acc);
        if (o == 0) atomicAdd(&deg[dn], 1.f);
    }
}

// ---------------- f32 -> bf16 conversions ----------------
__global__ void conv_x(const float* __restrict__ in, unsigned short* __restrict__ out, int n) {
    int g = blockIdx.x * blockDim.x + threadIdx.x;
    if (g < n) out[g] = f2bf(in[g]);
}

// W[k][i][o] f32 -> Wt[(k*OUT+o)][i] bf16
template <int IN, int OUT>
__global__ void conv_w(const float* __restrict__ W, unsigned short* __restrict__ wt, int total) {
    int g = blockIdx.x * blockDim.x + threadIdx.x;
    if (g >= total) return;
    int i = g % IN;
    int ko = g / IN;
    int k = ko / OUT, o = ko % OUT;
    wt[g] = f2bf(W[(size_t)k * IN * OUT + (size_t)i * OUT + o]);
}

// ---------------- MFMA y = x @ W  (y[n][ko] bf16) ----------------
// A = Wt (M-dim = ko), B = x (col-dim = n)  ->  lane stores 4 contiguous ko.
template <int IN>
__global__ __launch_bounds__(256) void gemm_y_mfma(const unsigned short* __restrict__ xb,
                                                   const unsigned short* __restrict__ wt,
                                                   unsigned short* __restrict__ y,
                                                   int N, int KO) {
    int wid = (blockIdx.x * 256 + threadIdx.x) >> 6;
    int lane = threadIdx.x & 63;
    int nTiles = N >> 4;
    int n0 = (wid % nTiles) << 4;
    int ko0 = (wid / nTiles) << 6;       // 64 ko per wave
    int l15 = lane & 15;
    int kk = (lane >> 4) << 3;           // 0,8,16,24

    f32x4 acc[4];
#pragma unroll
    for (int t = 0; t < 4; ++t) acc[t] = (f32x4){0.f, 0.f, 0.f, 0.f};

#pragma unroll
    for (int s = 0; s < IN / 32; ++s) {
        bf16x8 bfrag = *(const bf16x8*)(xb + (size_t)(n0 + l15) * IN + s * 32 + kk);
#pragma unroll
        for (int t = 0; t < 4; ++t) {
            bf16x8 afrag = *(const bf16x8*)(wt + (size_t)(ko0 + t * 16 + l15) * IN + s * 32 + kk);
            acc[t] = __builtin_amdgcn_mfma_f32_16x16x32_bf16(afrag, bfrag, acc[t], 0, 0, 0);
        }
    }
    int rbase = (lane >> 4) << 2;        // 4 contiguous ko per lane
#pragma unroll
    for (int t = 0; t < 4; ++t) {
        ushort4 sv;
        sv.x = f2bf(acc[t][0]);
        sv.y = f2bf(acc[t][1]);
        sv.z = f2bf(acc[t][2]);
        sv.w = f2bf(acc[t][3]);
        *(ushort4*)(y + (size_t)(n0 + l15) * KO + ko0 + t * 16 + rbase) = sv;
    }
}

// ---------------- per-edge gather from y table (table-driven) ----------------
template <int OUT>
__global__ void gather_edge_t(const unsigned short* __restrict__ y,
                              const float* __restrict__ bas,
                              const u64* __restrict__ kid,
                              const int* __restrict__ src,
                              const int* __restrict__ dst,
                              float* __restrict__ agg,
                              float* __restrict__ deg, int E) {
    int g = blockIdx.x * blockDim.x + threadIdx.x;
    int e = g / OUT;
    int o = g % OUT;
    if (e >= E) return;
    float4 q0 = *(const float4*)(bas + (size_t)e * 8);
    float4 q1 = *(const float4*)(bas + (size_t)e * 8 + 4);
    float b[8] = {q0.x, q0.y, q0.z, q0.w, q1.x, q1.y, q1.z, q1.w};
    u64 k8 = kid[e];
    int s = src[e], dn = dst[e];
    const unsigned short* yp = y + (size_t)s * (K3 * OUT) + o;
    float acc = 0.f;
#pragma unroll
    for (int c = 0; c < 8; ++c) {
        int kc = (int)((k8 >> (8 * c)) & 255u);
        acc = fmaf(b[c], bf2f(yp[(size_t)kc * OUT]), acc);
    }
    atomicAdd(&agg[(size_t)dn * OUT + o], acc);
    if (o == 0) atomicAdd(&deg[dn], 1.f);
}

// ---------------- fallback per-edge (used only if ws too small) ----------------
template <int IN, int OUT>
__global__ void spline_edge(const float* __restrict__ x,
                            const float* __restrict__ pseudo,
                            const float* __restrict__ W,
                            const int* __restrict__ src,
                            const int* __restrict__ dst,
                            float* __restrict__ agg,
                            float* __restrict__ deg, int E) {
    long long g = (long long)blockIdx.x * blockDim.x + threadIdx.x;
    int e = (int)(g / OUT);
    int o = (int)(g % OUT);
    if (e >= E) return;
    float bas[8]; int kidv[8];
    decode_edge(pseudo, e, bas, kidv);
    int s = src[e], dn = dst[e];
    const float* xp = x + (size_t)s * IN;
    float acc = 0.f;
#pragma unroll
    for (int c = 0; c < 8; ++c) {
        const float* Wp = W + (size_t)kidv[c] * IN * OUT + o;
        float sacc = 0.f;
        for (int i = 0; i < IN; ++i)
            sacc = fmaf(xp[i], Wp[(size_t)i * OUT], sacc);
        acc = fmaf(bas[c], sacc, acc);
    }
    atomicAdd(&agg[(size_t)dn * OUT + o], acc);
    if (o == 0) atomicAdd(&deg[dn], 1.f);
}

// ---------------- node finish: mean + root + bias + ELU ----------------
template <int IN, int OUT>
__global__ void node_finish(const float* __restrict__ agg,
                            const float* __restrict__ deg,
                            const float* __restrict__ x,
                            const float* __restrict__ root,
                            const float* __restrict__ bias,
                            float* __restrict__ out, int N) {
    int g = blockIdx.x * blockDim.x + threadIdx.x;
    if (g >= N * OUT) return;
    int n = g / OUT, o = g % OUT;
    float r = 0.f;
    for (int i = 0; i < IN; ++i)
        r = fmaf(x[(size_t)n * IN + i], root[(size_t)i * OUT + o], r);
    float dg = fmaxf(deg[n], 1.f);
    float val = agg[g] / dg + r + bias[o];
    out[g] = eluf(val);
}

// ---------------- max pool ----------------
template <int C>
__global__ void pool_scatter(const float* __restrict__ x,
                             const int* __restrict__ cluster,
                             unsigned* __restrict__ penc, int N) {
    int g = blockIdx.x * blockDim.x + threadIdx.x;
    if (g >= N * C) return;
    int n = g / C, c = g % C;
    atomicMax(&penc[(size_t)cluster[n] * C + c], enc_f(x[g]));
}

__global__ void pool_final(const unsigned* __restrict__ penc,
                           float* __restrict__ out, int M) {
    int g = blockIdx.x * blockDim.x + threadIdx.x;
    if (g >= M) return;
    float v = dec_f(penc[g]);
    out[g] = isfinite(v) ? v : 0.f;
}

// ---------------- FC head ----------------
__global__ void fc1_kernel(const float* __restrict__ xin,
                           const float* __restrict__ w,
                           const float* __restrict__ b,
                           float* __restrict__ out) {
    int bq = blockIdx.x;        // batch row (16)
    int p = threadIdx.x;        // 256 outputs
    const float* xr = xin + (size_t)bq * 1024;
    float acc = b[p];
    for (int q = 0; q < 1024; ++q)
        acc = fmaf(xr[q], w[(size_t)q * 256 + p], acc);
    out[(size_t)bq * 256 + p] = eluf(acc);
}

__global__ void fc2_ls_kernel(const float* __restrict__ xin,
                              const float* __restrict__ w,
                              const float* __restrict__ b,
                              float* __restrict__ out) {
    __shared__ float l[10];
    __shared__ float red[2];
    int bq = blockIdx.x;
    int t = threadIdx.x;        // 64
    if (t < 10) {
        const float* xr = xin + (size_t)bq * 256;
        float acc = b[t];
        for (int q = 0; q < 256; ++q)
            acc = fmaf(xr[q], w[(size_t)q * 10 + t], acc);
        l[t] = acc;
    }
    __syncthreads();
    if (t == 0) {
        float m = l[0];
        for (int i = 1; i < 10; ++i) m = fmaxf(m, l[i]);
        float s = 0.f;
        for (int i = 0; i < 10; ++i) s += expf(l[i] - m);
        red[0] = m;
        red[1] = logf(s);
    }
    __syncthreads();
    if (t < 10) out[(size_t)bq * 10 + t] = l[t] - red[0] - red[1];
}

inline unsigned blk(long long t) { return (unsigned)((t + 255) / 256); }

} // namespace

extern "C" void kernel_launch(void* const* d_in, const int* in_sizes, int n_in,
                              void* d_out, int out_size, void* d_ws, size_t ws_size,
                              hipStream_t stream) {
    const float* x0    = (const float*)d_in[0];
    const float* ps0   = (const float*)d_in[1];
    const float* ps1   = (const float*)d_in[2];
    const float* ps2   = (const float*)d_in[3];
    const float* ps3   = (const float*)d_in[4];
    const float* W1    = (const float*)d_in[5];
    const float* root1 = (const float*)d_in[6];
    const float* b1    = (const float*)d_in[7];
    const float* W2    = (const float*)d_in[8];
    const float* root2 = (const float*)d_in[9];
    const float* b2    = (const float*)d_in[10];
    const float* W3    = (const float*)d_in[11];
    const float* root3 = (const float*)d_in[12];
    const float* b3    = (const float*)d_in[13];
    const float* W4    = (const float*)d_in[14];
    const float* root4 = (const float*)d_in[15];
    const float* b4    = (const float*)d_in[16];
    const float* fc1w  = (const float*)d_in[17];
    const float* fc1b  = (const float*)d_in[18];
    const float* fc2w  = (const float*)d_in[19];
    const float* fc2b  = (const float*)d_in[20];
    const int* src0 = (const int*)d_in[21];
    const int* dst0 = (const int*)d_in[22];
    const int* src1 = (const int*)d_in[23];
    const int* dst1 = (const int*)d_in[24];
    const int* src2 = (const int*)d_in[25];
    const int* dst2 = (const int*)d_in[26];
    const int* src3 = (const int*)d_in[27];
    const int* dst3 = (const int*)d_in[28];
    const int* cl0  = (const int*)d_in[29];
    const int* cl1  = (const int*)d_in[30];
    const int* cl2  = (const int*)d_in[31];
    const int* cl3  = (const int*)d_in[32];

    float* ws = (float*)d_ws;
    float* out = (float*)d_out;
    float* bas = ws + OFF_BAS;
    u64*   kid = (u64*)(ws + OFF_KID);
    unsigned short* xb = (unsigned short*)(ws + OFF_XB);
    unsigned short* wt = (unsigned short*)(ws + OFF_WT);
    unsigned short* yb = (unsigned short*)(ws + OFF_Y);
    const bool use_tab = (ws_size >= WS_NEED_TAB);
    const bool use_y   = (ws_size >= WS_NEED_Y);

    // zero accumulators + degree counters
    hipMemsetAsync(ws + OFF_AGG1, 0, ZERO_END * sizeof(float), stream);
    // init pool-max encoded buffers to enc(-inf)
    init_enc<<<blk(PENC_TOTAL), 256, 0, stream>>>((unsigned*)(ws + OFF_PENC1), (int)PENC_TOTAL);

    // ---- layer 1: conv(1->32) on N0, pool -> N1 ----
    if (use_tab) {
        decode_basis<<<blk(E0), 256, 0, stream>>>(ps0, bas, kid, E0);
        spline_l1_t<<<E0 / 64, 256, 0, stream>>>(x0, bas, kid, W1, src0, dst0,
                                                 ws + OFF_AGG1, ws + OFF_DEG1, E0);
    } else {
        spline_l1<<<E0 / 32, 256, 0, stream>>>(x0, ps0, W1, src0, dst0,
                                               ws + OFF_AGG1, ws + OFF_DEG1, E0);
    }
    node_finish<1, 32><<<blk((long long)N0 * 32), 256, 0, stream>>>(
        ws + OFF_AGG1, ws + OFF_DEG1, x0, root1, b1, ws + OFF_X1, N0);
    pool_scatter<32><<<blk((long long)N0 * 32), 256, 0, stream>>>(
        ws + OFF_X1, cl0, (unsigned*)(ws + OFF_PENC1), N0);
    pool_final<<<blk((long long)N1 * 32), 256, 0, stream>>>(
        (unsigned*)(ws + OFF_PENC1), ws + OFF_P1, N1 * 32);

    // ---- layer 2: conv(32->64) on N1, pool -> N2 ----
    if (use_y) {
        conv_x<<<blk((long long)N1 * 32), 256, 0, stream>>>(ws + OFF_P1, xb, N1 * 32);
        conv_w<32, 64><<<blk((long long)K3 * 64 * 32), 256, 0, stream>>>(W2, wt, K3 * 64 * 32);
        gemm_y_mfma<32><<<(N1 / 16) * (K3 * 64 / 64) / 4, 256, 0, stream>>>(xb, wt, yb, N1, K3 * 64);
        decode_basis<<<blk(E1), 256, 0, stream>>>(ps1, bas, kid, E1);
        gather_edge_t<64><<<blk((long long)E1 * 64), 256, 0, stream>>>(
            yb, bas, kid, src1, dst1, ws + OFF_AGG2, ws + OFF_DEG2, E1);
    } else {
        spline_edge<32, 64><<<blk((long long)E1 * 64), 256, 0, stream>>>(
            ws + OFF_P1, ps1, W2, src1, dst1, ws + OFF_AGG2, ws + OFF_DEG2, E1);
    }
    node_finish<32, 64><<<blk((long long)N1 * 64), 256, 0, stream>>>(
        ws + OFF_AGG2, ws + OFF_DEG2, ws + OFF_P1, root2, b2, ws + OFF_X2, N1);
    pool_scatter<64><<<blk((long long)N1 * 64), 256, 0, stream>>>(
        ws + OFF_X2, cl1, (unsigned*)(ws + OFF_PENC2), N1);
    pool_final<<<blk((long long)N2 * 64), 256, 0, stream>>>(
        (unsigned*)(ws + OFF_PENC2), ws + OFF_P2, N2 * 64);

    // ---- layer 3: conv(64->64) on N2, pool -> N3 ----
    if (use_y) {
        conv_x<<<blk((long long)N2 * 64), 256, 0, stream>>>(ws + OFF_P2, xb, N2 * 64);
        conv_w<64, 64><<<blk((long long)K3 * 64 * 64), 256, 0, stream>>>(W3, wt, K3 * 64 * 64);
        gemm_y_mfma<64><<<(N2 / 16) * (K3 * 64 / 64) / 4, 256, 0, stream>>>(xb, wt, yb, N2, K3 * 64);
        decode_basis<<<blk(E2), 256, 0, stream>>>(ps2, bas, kid, E2);
        gather_edge_t<64><<<blk((long long)E2 * 64), 256, 0, stream>>>(
            yb, bas, kid, src2, dst2, ws + OFF_AGG3, ws + OFF_DEG3, E2);
    } else {
        spline_edge<64, 64><<<blk((long long)E2 * 64), 256, 0, stream>>>(
            ws + OFF_P2, ps2, W3, src2, dst2, ws + OFF_AGG3, ws + OFF_DEG3, E2);
    }
    node_finish<64, 64><<<blk((long long)N2 * 64), 256, 0, stream>>>(
        ws + OFF_AGG3, ws + OFF_DEG3, ws + OFF_P2, root3, b3, ws + OFF_X3, N2);
    pool_scatter<64><<<blk((long long)N2 * 64), 256, 0, stream>>>(
        ws + OFF_X3, cl2, (unsigned*)(ws + OFF_PENC3), N2);
    pool_final<<<blk((long long)N3 * 64), 256, 0, stream>>>(
        (unsigned*)(ws + OFF_PENC3), ws + OFF_P3, N3 * 64);

    // ---- layer 4: conv(64->128) on N3, pool -> V=128 ----
    if (use_y) {
        conv_x<<<blk((long long)N3 * 64), 256, 0, stream>>>(ws + OFF_P3, xb, N3 * 64);
        conv_w<64, 128><<<blk((long long)K3 * 128 * 64), 256, 0, stream>>>(W4, wt, K3 * 128 * 64);
        gemm_y_mfma<64><<<(N3 / 16) * (K3 * 128 / 64) / 4, 256, 0, stream>>>(xb, wt, yb, N3, K3 * 128);
        decode_basis<<<blk(E3), 256, 0, stream>>>(ps3, bas, kid, E3);
        gather_edge_t<128><<<blk((long long)E3 * 128), 256, 0, stream>>>(
            yb, bas, kid, src3, dst3, ws + OFF_AGG4, ws + OFF_DEG4, E3);
    } else {
        spline_edge<64, 128><<<blk((long long)E3 * 128), 256, 0, stream>>>(
            ws + OFF_P3, ps3, W4, src3, dst3, ws + OFF_AGG4, ws + OFF_DEG4, E3);
    }
    node_finish<64, 128><<<blk((long long)N3 * 128), 256, 0, stream>>>(
        ws + OFF_AGG4, ws + OFF_DEG4, ws + OFF_P3, root4, b4, ws + OFF_X4, N3);
    pool_scatter<128><<<blk((long long)N3 * 128), 256, 0, stream>>>(
        ws + OFF_X4, cl3, (unsigned*)(ws + OFF_PENC4), N3);
    pool_final<<<blk((long long)NV * 128), 256, 0, stream>>>(
        (unsigned*)(ws + OFF_PENC4), ws + OFF_P4, NV * 128);

    // ---- FC head ----
    fc1_kernel<<<16, 256, 0, stream>>>(ws + OFF_P4, fc1w, fc1b, ws + OFF_FC1);
    fc2_ls_kernel<<<16, 64, 0, stream>>>(ws + OFF_FC1, fc2w, fc2b, out);
}